// Round 7
// baseline (1157.758 us; speedup 1.0000x reference)
//
#include <hip/hip_runtime.h>

#define N_NODES 16384
#define E_EDGES 524288
#define IN_DIM  256
#define OUT_DIM 128
#define CAP     512    // per-row bucket capacity; degree ~ Poisson(32), max ~70

// ---- K1: x = input @ W, fused per-row squared norm; also zeroes deg[].
// 32 rows/block, 256 threads; thread (g=t>>5, c=t&31) owns rows 4g..4g+3,
// cols 4c..4c+3 in registers. LDS reads are b128, 2-way broadcast (free).
__global__ __launch_bounds__(256) void gemm_norm(
    const float* __restrict__ inp, const float* __restrict__ W,
    float* __restrict__ x, float* __restrict__ nrm2, int* __restrict__ deg) {
    const int t  = threadIdx.x;
    const int g  = t >> 5;
    const int c  = t & 31;
    const int n0 = blockIdx.x * 32;

    // fold deg zeroing into this kernel (stream order makes it visible to K2)
    if (blockIdx.x < 64) deg[blockIdx.x * 256 + t] = 0;

    __shared__ float4 sA4[32 * (IN_DIM / 4)];          // 32 KB
    const float4* inp4 = (const float4*)(inp + (size_t)n0 * IN_DIM);
#pragma unroll
    for (int i = 0; i < 8; ++i) sA4[t + 256 * i] = inp4[t + 256 * i];
    __syncthreads();

    const float4* W4 = (const float4*)W;               // [IN_DIM][32]
    float4 acc[4];
#pragma unroll
    for (int i = 0; i < 4; ++i) acc[i] = make_float4(0.f, 0.f, 0.f, 0.f);

    for (int kq = 0; kq < IN_DIM / 4; ++kq) {
        float4 w0 = W4[(kq * 4 + 0) * 32 + c];
        float4 w1 = W4[(kq * 4 + 1) * 32 + c];
        float4 w2 = W4[(kq * 4 + 2) * 32 + c];
        float4 w3 = W4[(kq * 4 + 3) * 32 + c];
#pragma unroll
        for (int i = 0; i < 4; ++i) {
            float4 s = sA4[(4 * g + i) * 64 + kq];
            acc[i].x += s.x * w0.x + s.y * w1.x + s.z * w2.x + s.w * w3.x;
            acc[i].y += s.x * w0.y + s.y * w1.y + s.z * w2.y + s.w * w3.y;
            acc[i].z += s.x * w0.z + s.y * w1.z + s.z * w2.z + s.w * w3.z;
            acc[i].w += s.x * w0.w + s.y * w1.w + s.z * w2.w + s.w * w3.w;
        }
    }

    float4* x4 = (float4*)x;
#pragma unroll
    for (int i = 0; i < 4; ++i) {
        const int r = n0 + 4 * g + i;
        x4[(size_t)r * 32 + c] = acc[i];
        float p = acc[i].x * acc[i].x + acc[i].y * acc[i].y
                + acc[i].z * acc[i].z + acc[i].w * acc[i].w;
#pragma unroll
        for (int off = 16; off > 0; off >>= 1) p += __shfl_xor(p, off);
        if (c == 0) nrm2[r] = p;
    }
}

// ---- K2: bucket the column indices by row
__global__ __launch_bounds__(256) void bucket_fill(
    const int* __restrict__ rows, const int* __restrict__ cols,
    int* __restrict__ deg, int* __restrict__ bucket) {
    const int e = blockIdx.x * blockDim.x + threadIdx.x;
    const int r = rows[e];
    int k = atomicAdd(&deg[r], 1);
    if (k < CAP) bucket[(size_t)r * CAP + k] = cols[e];
}

// ---- K3: fused per-row zero + scores + softmax-sum + scatter.
// ZERO-FIRST ordering: the 64 KB row-zero store stream is issued before the
// gather/score phase so store drain and gather latency overlap; the single
// __syncthreads() (vmcnt(0) semantics) guarantees zeros landed before atomics.
// s = (sum_d relu(x_r[d]*x_c[d]) * a[d]) * rsqrt(n2_r*n2_c)  (== ref exactly)
// ex = s>0 ? exp(s) : 0  (shift-free softmax: the ref's exp(s-smax)/ssum is
// shift-invariant and exp can't overflow). ssum==0 row -> uniform 1/deg,
// matching ref (all s==NEG_BIG => all shifted exps == 1).
__global__ __launch_bounds__(256) void fused_row(
    const float* __restrict__ x, const float* __restrict__ nrm2,
    const int* __restrict__ deg, const int* __restrict__ bucket,
    const float* __restrict__ a, float* __restrict__ A) {
    const int r    = blockIdx.x;
    const int t    = threadIdx.x;
    const int hw   = t >> 5;
    const int lane = t & 31;
    int d = deg[r]; if (d > CAP) d = CAP;

    // phase 1: fire-and-forget zero of this A row (coalesced float4 stores)
    float4* Arow4 = (float4*)(A + (size_t)r * N_NODES);
    float4 z = make_float4(0.f, 0.f, 0.f, 0.f);
#pragma unroll
    for (int k = 0; k < 16; ++k) Arow4[t + 256 * k] = z;

    __shared__ float sex[CAP];
    __shared__ float ssum_s;
    if (t == 0) ssum_s = 0.f;

    // phase 2: gather + score while the stores drain
    const float4* x4 = (const float4*)x;
    const float4* a4 = (const float4*)a;
    const int* buk = bucket + (size_t)r * CAP;
    float4 xi = x4[(size_t)r * 32 + lane];
    float4 av = a4[lane];
    const float n2r = nrm2[r];

    float local = 0.f;
    for (int i = hw; i < d; i += 8) {
        int c = buk[i];
        float4 xj = x4[(size_t)c * 32 + lane];
        float tv = fmaxf(xi.x * xj.x, 0.f) * av.x
                 + fmaxf(xi.y * xj.y, 0.f) * av.y
                 + fmaxf(xi.z * xj.z, 0.f) * av.z
                 + fmaxf(xi.w * xj.w, 0.f) * av.w;
#pragma unroll
        for (int off = 16; off > 0; off >>= 1) tv += __shfl_xor(tv, off);
        if (lane == 0) {
            float s = tv * rsqrtf(n2r * nrm2[c]);
            float ex = (s > 0.f) ? expf(s) : 0.f;
            sex[i] = ex;
            local += ex;
        }
    }
    if (lane == 0 && local != 0.f) atomicAdd(&ssum_s, local);
    __syncthreads();   // drains zero stores (vmcnt 0) + publishes sex/ssum
    const float ssum = ssum_s;

    // phase 3: scatter into the freshly-zeroed row (lines are in our L2)
    if (d == 0) return;
    float* Arow = A + (size_t)r * N_NODES;
    if (ssum > 0.f) {
        const float inv = 1.0f / ssum;
        for (int i = t; i < d; i += 256) {
            float ex = sex[i];
            if (ex == 0.f) continue;   // reference value is exactly 0 here
            atomicAdd(&Arow[buk[i]], ex * inv);
        }
    } else {
        const float u = 1.0f / (float)d;
        for (int i = t; i < d; i += 256)
            atomicAdd(&Arow[buk[i]], u);
    }
}

extern "C" void kernel_launch(void* const* d_in, const int* in_sizes, int n_in,
                              void* d_out, int out_size, void* d_ws, size_t ws_size,
                              hipStream_t stream) {
    const float* inp  = (const float*)d_in[0];
    const int*   edge = (const int*)d_in[1];   // [2, E]: rows then cols
    const float* W    = (const float*)d_in[2];
    const float* a    = (const float*)d_in[3];
    const int* rows = edge;
    const int* cols = edge + E_EDGES;

    float* x = (float*)d_out;                          // [N, OUT_DIM]
    float* A = x + (size_t)N_NODES * OUT_DIM;          // [N, N]

    float* nrm2   = (float*)d_ws;                      // N floats
    int*   deg    = (int*)(nrm2 + N_NODES);            // N ints
    int*   bucket = deg + N_NODES;                     // N*CAP ints (32 MB)

    gemm_norm<<<N_NODES / 32, 256, 0, stream>>>(inp, W, x, nrm2, deg);
    bucket_fill<<<E_EDGES / 256, 256, 0, stream>>>(rows, cols, deg, bucket);
    fused_row<<<N_NODES, 256, 0, stream>>>(x, nrm2, deg, bucket, a, A);
}

// Round 8
// 1135.196 us; speedup vs baseline: 1.0199x; 1.0199x over previous
//
#include <hip/hip_runtime.h>

#define N_NODES 16384
#define E_EDGES 524288
#define IN_DIM  256
#define OUT_DIM 128
#define CAP     512    // per-row bucket capacity; degree ~ Poisson(32), max ~70
#define GEMM_BLOCKS (N_NODES / 32)          // 512
#define BUCKET_BLOCKS (E_EDGES / 256)       // 2048

// ---- K1 (merged): blocks [0, GEMM_BLOCKS) do x = input @ W + row norms;
// blocks [GEMM_BLOCKS, ...) bucket edge columns by row. The two halves share
// no data (deg is pre-zeroed by memsetAsync), so the atomic-bound bucketing
// overlaps the compute-bound GEMM instead of serializing behind it.
__global__ __launch_bounds__(256) void gemm_bucket(
    const float* __restrict__ inp, const float* __restrict__ W,
    float* __restrict__ x, float* __restrict__ nrm2,
    const int* __restrict__ rows, const int* __restrict__ cols,
    int* __restrict__ deg, int* __restrict__ bucket) {
    const int t = threadIdx.x;

    if (blockIdx.x >= GEMM_BLOCKS) {
        // ---- bucket half: one thread per edge
        const int e = (blockIdx.x - GEMM_BLOCKS) * 256 + t;
        const int r = rows[e];
        int k = atomicAdd(&deg[r], 1);
        if (k < CAP) bucket[(size_t)r * CAP + k] = cols[e];
        return;
    }

    // ---- GEMM half: 32 rows/block; thread (g=t>>5, c=t&31) owns a 4x4 tile.
    const int g  = t >> 5;
    const int c  = t & 31;
    const int n0 = blockIdx.x * 32;

    __shared__ float4 sA4[32 * (IN_DIM / 4)];          // 32 KB
    const float4* inp4 = (const float4*)(inp + (size_t)n0 * IN_DIM);
#pragma unroll
    for (int i = 0; i < 8; ++i) sA4[t + 256 * i] = inp4[t + 256 * i];
    __syncthreads();

    const float4* W4 = (const float4*)W;               // [IN_DIM][32]
    float4 acc[4];
#pragma unroll
    for (int i = 0; i < 4; ++i) acc[i] = make_float4(0.f, 0.f, 0.f, 0.f);

    for (int kq = 0; kq < IN_DIM / 4; ++kq) {
        float4 w0 = W4[(kq * 4 + 0) * 32 + c];
        float4 w1 = W4[(kq * 4 + 1) * 32 + c];
        float4 w2 = W4[(kq * 4 + 2) * 32 + c];
        float4 w3 = W4[(kq * 4 + 3) * 32 + c];
#pragma unroll
        for (int i = 0; i < 4; ++i) {
            float4 s = sA4[(4 * g + i) * 64 + kq];
            acc[i].x += s.x * w0.x + s.y * w1.x + s.z * w2.x + s.w * w3.x;
            acc[i].y += s.x * w0.y + s.y * w1.y + s.z * w2.y + s.w * w3.y;
            acc[i].z += s.x * w0.z + s.y * w1.z + s.z * w2.z + s.w * w3.z;
            acc[i].w += s.x * w0.w + s.y * w1.w + s.z * w2.w + s.w * w3.w;
        }
    }

    float4* x4 = (float4*)x;
#pragma unroll
    for (int i = 0; i < 4; ++i) {
        const int r = n0 + 4 * g + i;
        x4[(size_t)r * 32 + c] = acc[i];
        float p = acc[i].x * acc[i].x + acc[i].y * acc[i].y
                + acc[i].z * acc[i].z + acc[i].w * acc[i].w;
#pragma unroll
        for (int off = 16; off > 0; off >>= 1) p += __shfl_xor(p, off);
        if (c == 0) nrm2[r] = p;
    }
}

// ---- K2: fused per-row scores + softmax-sum + zero row + scatter.
// Round-6 ordering (measured best): gather/score, barrier-free zero stores,
// single __syncthreads (vmcnt(0) drain) before the atomics.
// s = (sum_d relu(x_r[d]*x_c[d]) * a[d]) * rsqrt(n2_r*n2_c)  (== ref exactly)
// ex = s>0 ? exp(s) : 0  (shift-free softmax: the ref's exp(s-smax)/ssum is
// shift-invariant and exp can't overflow). ssum==0 row -> uniform 1/deg,
// matching ref (all s==NEG_BIG => all shifted exps == 1).
__global__ __launch_bounds__(256) void fused_row(
    const float* __restrict__ x, const float* __restrict__ nrm2,
    const int* __restrict__ deg, const int* __restrict__ bucket,
    const float* __restrict__ a, float* __restrict__ A) {
    const int r    = blockIdx.x;
    const int t    = threadIdx.x;
    const int hw   = t >> 5;
    const int lane = t & 31;
    int d = deg[r]; if (d > CAP) d = CAP;

    __shared__ float sex[CAP];
    __shared__ float ssum_s;
    if (t == 0) ssum_s = 0.f;

    const float4* x4 = (const float4*)x;
    const float4* a4 = (const float4*)a;
    const int* buk = bucket + (size_t)r * CAP;
    float4 xi = x4[(size_t)r * 32 + lane];
    float4 av = a4[lane];
    const float n2r = nrm2[r];
    __syncthreads();

    float local = 0.f;
    for (int i = hw; i < d; i += 8) {
        int c = buk[i];
        float4 xj = x4[(size_t)c * 32 + lane];
        float tv = fmaxf(xi.x * xj.x, 0.f) * av.x
                 + fmaxf(xi.y * xj.y, 0.f) * av.y
                 + fmaxf(xi.z * xj.z, 0.f) * av.z
                 + fmaxf(xi.w * xj.w, 0.f) * av.w;
#pragma unroll
        for (int off = 16; off > 0; off >>= 1) tv += __shfl_xor(tv, off);
        if (lane == 0) {
            float s = tv * rsqrtf(n2r * nrm2[c]);
            float ex = (s > 0.f) ? expf(s) : 0.f;
            sex[i] = ex;
            local += ex;
        }
    }
    if (lane == 0 && local != 0.f) atomicAdd(&ssum_s, local);

    // zero this A row with coalesced float4 stores (lines stay in our L2
    // for the atomics below)
    float4* Arow4 = (float4*)(A + (size_t)r * N_NODES);
    float4 z = make_float4(0.f, 0.f, 0.f, 0.f);
#pragma unroll
    for (int k = 0; k < 16; ++k) Arow4[t + 256 * k] = z;
    __syncthreads();   // vmcnt(0) drain + publishes sex/ssum
    const float ssum = ssum_s;

    if (d == 0) return;
    float* Arow = A + (size_t)r * N_NODES;
    if (ssum > 0.f) {
        const float inv = 1.0f / ssum;
        for (int i = t; i < d; i += 256) {
            float ex = sex[i];
            if (ex == 0.f) continue;   // reference value is exactly 0 here
            atomicAdd(&Arow[buk[i]], ex * inv);
        }
    } else {
        const float u = 1.0f / (float)d;
        for (int i = t; i < d; i += 256)
            atomicAdd(&Arow[buk[i]], u);
    }
}

extern "C" void kernel_launch(void* const* d_in, const int* in_sizes, int n_in,
                              void* d_out, int out_size, void* d_ws, size_t ws_size,
                              hipStream_t stream) {
    const float* inp  = (const float*)d_in[0];
    const int*   edge = (const int*)d_in[1];   // [2, E]: rows then cols
    const float* W    = (const float*)d_in[2];
    const float* a    = (const float*)d_in[3];
    const int* rows = edge;
    const int* cols = edge + E_EDGES;

    float* x = (float*)d_out;                          // [N, OUT_DIM]
    float* A = x + (size_t)N_NODES * OUT_DIM;          // [N, N]

    float* nrm2   = (float*)d_ws;                      // N floats
    int*   deg    = (int*)(nrm2 + N_NODES);            // N ints
    int*   bucket = deg + N_NODES;                     // N*CAP ints (32 MB)

    hipMemsetAsync(deg, 0, N_NODES * sizeof(int), stream);
    gemm_bucket<<<GEMM_BLOCKS + BUCKET_BLOCKS, 256, 0, stream>>>(
        inp, W, x, nrm2, rows, cols, deg, bucket);
    fused_row<<<N_NODES, 256, 0, stream>>>(x, nrm2, deg, bucket, a, A);
}